// Round 6
// baseline (714.178 us; speedup 1.0000x reference)
//
#include <hip/hip_runtime.h>

#define TOK    16384
#define HD     1024
#define ID     4096
#define NE     4
#define MAXMT  131   // worst-case M-tiles at BM=128

typedef __attribute__((ext_vector_type(4))) float f32x4;
typedef __attribute__((ext_vector_type(8))) short bf16x8;
typedef unsigned int u32;

static __device__ __forceinline__ unsigned short f2bf(float f) {
  unsigned u = __float_as_uint(f);
  u += 0x7FFFu + ((u >> 16) & 1u);   // RNE
  return (unsigned short)(u >> 16);
}

static __device__ __forceinline__ void gl16(const void* g, void* l) {
  __builtin_amdgcn_global_load_lds((const __attribute__((address_space(1))) u32*)g,
                                   (__attribute__((address_space(3))) u32*)l, 16, 0, 0);
}

static __device__ __forceinline__ void barx() {
  asm volatile("" ::: "memory");
  __builtin_amdgcn_s_barrier();
  asm volatile("" ::: "memory");
}

// ---------------- routing ----------------
__global__ void k_route0(const int* __restrict__ ids, int* __restrict__ meta) {
  __shared__ int cnt[4];
  int t = threadIdx.x;
  if (t < 4) cnt[t] = 0;
  __syncthreads();
  int l0 = 0, l1 = 0, l2 = 0, l3 = 0;
  for (int i = t; i < TOK; i += 256) {
    int e = ids[i] & 3;
    l0 += (e == 0); l1 += (e == 1); l2 += (e == 2); l3 += (e == 3);
  }
  atomicAdd(&cnt[0], l0); atomicAdd(&cnt[1], l1);
  atomicAdd(&cnt[2], l2); atomicAdd(&cnt[3], l3);
  __syncthreads();
  if (t == 0) {
    int o = 0;
    for (int e = 0; e < 4; ++e) { meta[e] = o; meta[8 + e] = o; o += cnt[e]; }
    meta[4] = o;
  }
}

__global__ void k_route1(const int* __restrict__ ids, int* __restrict__ meta,
                         int* __restrict__ perm) {
  int i = blockIdx.x * 256 + threadIdx.x;
  if (i < TOK) {
    int e = ids[i] & 3;
    int s = atomicAdd(&meta[8 + e], 1);
    perm[s] = i;
  }
}

// ---------------- f32 -> bf16 copy (hidden states) ----------------
__global__ void k_conv(const float* __restrict__ s, unsigned short* __restrict__ d, int n8) {
  int i = blockIdx.x * blockDim.x + threadIdx.x;
  int st = gridDim.x * blockDim.x;
  for (; i < n8; i += st) {
    const f32x4* p = (const f32x4*)(s + ((size_t)i << 3));
    f32x4 a = p[0], b = p[1];
    union { unsigned short u[8]; uint4 q; } o;
    o.u[0] = f2bf(a.x); o.u[1] = f2bf(a.y); o.u[2] = f2bf(a.z); o.u[3] = f2bf(a.w);
    o.u[4] = f2bf(b.x); o.u[5] = f2bf(b.y); o.u[6] = f2bf(b.z); o.u[7] = f2bf(b.w);
    *(uint4*)(d + ((size_t)i << 3)) = o.q;
  }
}

// ------- fused transpose+convert for all 12 weight matrices -------
__global__ void k_tr12(const float* __restrict__ gw, const float* __restrict__ uw,
                       const float* __restrict__ dw, unsigned short* __restrict__ gT,
                       unsigned short* __restrict__ uT, unsigned short* __restrict__ dT) {
  __shared__ float tile[64][65];
  int z = blockIdx.y;
  const float* s; unsigned short* d; int R, C, lg;
  if (z < 8) {
    R = HD; C = ID; lg = 6;
    int m = z & 3;
    if (z < 4) { s = gw + (size_t)m * R * C; d = gT + (size_t)m * R * C; }
    else       { s = uw + (size_t)m * R * C; d = uT + (size_t)m * R * C; }
  } else {
    R = ID; C = HD; lg = 4;
    int m = z - 8;
    s = dw + (size_t)m * R * C; d = dT + (size_t)m * R * C;
  }
  int bx = blockIdx.x;
  int tx = bx & ((1 << lg) - 1), ty = bx >> lg;
  int r0 = ty << 6, c0 = tx << 6;
  int t = threadIdx.x;
  int lr = t >> 4, lc = (t & 15) << 2;
  #pragma unroll
  for (int it = 0; it < 4; ++it) {
    int r = lr + (it << 4);
    f32x4 v = *(const f32x4*)(s + (size_t)(r0 + r) * C + c0 + lc);
    tile[r][lc] = v.x; tile[r][lc + 1] = v.y; tile[r][lc + 2] = v.z; tile[r][lc + 3] = v.w;
  }
  __syncthreads();
  int c = t >> 2, rb = (t & 3) << 4;
  union { unsigned short u[16]; uint4 q[2]; } o;
  #pragma unroll
  for (int j = 0; j < 16; ++j) o.u[j] = f2bf(tile[rb + j][c]);
  uint4* dp = (uint4*)(d + (size_t)(c0 + c) * R + r0 + rb);
  dp[0] = o.q[0]; dp[1] = o.q[1];
}

// ---------------- GEMM1 v6: round-1 128x128 dual G/U structure, m97 DMA staging ----
// Per K-step: barrier -> global_load_lds (12) -> vmcnt(0) -> barrier -> ds_read + MFMA.
// LDS single-buffered: A|G|U 16KB each. Swizzle: global src k-slot ^= (row&7),
// linear LDS dest, ds_read applies same XOR (round-3-validated involution).
#define MFMA16 __builtin_amdgcn_mfma_f32_16x16x32_bf16

__global__ __launch_bounds__(256, 2) void k_gemm1(
    const unsigned short* __restrict__ hid,   // [TOK][HD] bf16
    const unsigned short* __restrict__ gT,    // [NE][ID][HD] bf16
    const unsigned short* __restrict__ uT,    // [NE][ID][HD] bf16
    const int* __restrict__ meta,
    const int* __restrict__ perm,
    unsigned short* __restrict__ act) {       // [TOK][ID] bf16, slot-ordered
  __shared__ __align__(16) char smem[49152];
  int offs[5];
  #pragma unroll
  for (int i = 0; i < 5; ++i) offs[i] = meta[i];
  // chunked XCD swizzle: 4192 = 131*32 blocks, %8==0; same-mt blocks share an XCD.
  int bid = blockIdx.x;
  int logical = (bid & 7) * (MAXMT * 32 / 8) + (bid >> 3);
  int mt = logical >> 5;
  int ny = logical & 31;
  int e = -1, mloc = 0, base = 0;
  #pragma unroll
  for (int ee = 0; ee < 4; ++ee) {
    int tiles = (offs[ee + 1] - offs[ee] + 127) >> 7;
    if (e < 0 && mt < base + tiles) { e = ee; mloc = mt - base; }
    base += tiles;
  }
  if (e < 0) return;
  int slot0 = offs[e] + (mloc << 7);
  int send = offs[e + 1];
  int tid = threadIdx.x, lane = tid & 63, wid = tid >> 6;
  int n0 = ny << 7;

  // ---- staging sources (inverse-swizzled) ----
  const unsigned short* gb = gT + (size_t)e * ID * HD;
  const unsigned short* ub = uT + (size_t)e * ID * HD;
  int rsub = tid >> 3;                        // 0..31: row within sweep
  int ks = tid & 7;                           // dest 16B k-slot
  const unsigned short* srcA[4];
  const unsigned short* srcG[4];
  const unsigned short* srcU[4];
  #pragma unroll
  for (int j = 0; j < 4; ++j) {
    int r = j * 32 + rsub;                    // tile row 0..127
    int ko = (ks ^ (r & 7)) << 3;             // element offset of source slot
    int slot = slot0 + r;
    int pr = perm[slot < send ? slot : slot0];
    srcA[j] = hid + (size_t)pr * HD + ko;
    srcG[j] = gb + (size_t)(n0 + r) * HD + ko;
    srcU[j] = ub + (size_t)(n0 + r) * HD + ko;
  }
  int dstl = tid << 4;                        // + j*4096 per sweep (linear)

  // ---- fragment read offsets (kk=1 via ^64; slot XOR row&7) ----
  int wm = wid >> 1, wn = wid & 1;
  int r16 = lane & 15, kg = lane >> 4;
  int offA[4], offG[4], offU[4];
  #pragma unroll
  for (int m = 0; m < 4; ++m) {
    int r = wm * 64 + m * 16 + r16;
    offA[m] = r * 128 + ((kg ^ (r & 7)) << 4);
  }
  #pragma unroll
  for (int n = 0; n < 4; ++n) {
    int r = wn * 64 + n * 16 + r16;
    int o = r * 128 + ((kg ^ (r & 7)) << 4);
    offG[n] = 16384 + o;
    offU[n] = 32768 + o;
  }

  f32x4 ag[4][4], au[4][4];
  #pragma unroll
  for (int m = 0; m < 4; ++m)
    #pragma unroll
    for (int n = 0; n < 4; ++n) { ag[m][n] = (f32x4){0,0,0,0}; au[m][n] = (f32x4){0,0,0,0}; }

  for (int t = 0; t < HD / 64; ++t) {
    barx();                                   // prior reads consumed (lgkm before MFMA)
    int ko = t * 64;
    #pragma unroll
    for (int j = 0; j < 4; ++j) gl16(srcA[j] + ko, smem + j * 4096 + dstl);
    #pragma unroll
    for (int j = 0; j < 4; ++j) gl16(srcG[j] + ko, smem + 16384 + j * 4096 + dstl);
    #pragma unroll
    for (int j = 0; j < 4; ++j) gl16(srcU[j] + ko, smem + 32768 + j * 4096 + dstl);
    asm volatile("s_waitcnt vmcnt(0)" ::: "memory");
    barx();                                   // all waves' DMA landed
    #pragma unroll
    for (int kk = 0; kk < 2; ++kk) {
      bf16x8 fa[4], fg[4], fu[4];
      #pragma unroll
      for (int m = 0; m < 4; ++m) fa[m] = *(const bf16x8*)(smem + (offA[m] ^ (kk << 6)));
      #pragma unroll
      for (int n = 0; n < 4; ++n) {
        fg[n] = *(const bf16x8*)(smem + (offG[n] ^ (kk << 6)));
        fu[n] = *(const bf16x8*)(smem + (offU[n] ^ (kk << 6)));
      }
      #pragma unroll
      for (int m = 0; m < 4; ++m)
        #pragma unroll
        for (int n = 0; n < 4; ++n) {
          ag[m][n] = MFMA16(fa[m], fg[n], ag[m][n], 0, 0, 0);
          au[m][n] = MFMA16(fa[m], fu[n], au[m][n], 0, 0, 0);
        }
    }
  }

  // ---- epilogue: silu(g)*u -> act ----
  #pragma unroll
  for (int m = 0; m < 4; ++m) {
    int lr = (wm << 6) + (m << 4) + (kg << 2);
    #pragma unroll
    for (int n = 0; n < 4; ++n) {
      int col = n0 + (wn << 6) + (n << 4) + r16;
      #pragma unroll
      for (int r = 0; r < 4; ++r) {
        int slot = slot0 + lr + r;
        if (slot < send) {
          float g = ag[m][n][r];
          float u = au[m][n][r];
          float y = (g / (1.f + __expf(-g))) * u;
          act[(size_t)slot * ID + col] = f2bf(y);
        }
      }
    }
  }
}

// ---------------- GEMM2 v6: m97 DMA staging, 128x128, K=4096 ----------------
__global__ __launch_bounds__(256, 3) void k_gemm2(
    const unsigned short* __restrict__ act,   // [TOK][ID] bf16
    const unsigned short* __restrict__ dT,    // [NE][HD][ID] bf16
    const int* __restrict__ meta,
    const int* __restrict__ perm,
    float* __restrict__ out) {                // [TOK][HD] f32
  __shared__ __align__(16) char smem[32768];
  int offs[5];
  #pragma unroll
  for (int i = 0; i < 5; ++i) offs[i] = meta[i];
  int bid = blockIdx.x;                       // 1048 = 131*8
  int logical = (bid & 7) * (MAXMT * 8 / 8) + (bid >> 3);
  int mt = logical >> 3;
  int nyy = logical & 7;
  int e = -1, mloc = 0, base = 0;
  #pragma unroll
  for (int ee = 0; ee < 4; ++ee) {
    int tiles = (offs[ee + 1] - offs[ee] + 127) >> 7;
    if (e < 0 && mt < base + tiles) { e = ee; mloc = mt - base; }
    base += tiles;
  }
  if (e < 0) return;
  int slot0 = offs[e] + (mloc << 7);
  int send = offs[e + 1];
  int tid = threadIdx.x, lane = tid & 63, wid = tid >> 6;
  int n0 = nyy << 7;
  const unsigned short* dbase = dT + (size_t)e * HD * ID;

  int rsub = tid >> 3;
  int ks = tid & 7;
  const unsigned short* srcA[4];
  const unsigned short* srcB[4];
  #pragma unroll
  for (int j = 0; j < 4; ++j) {
    int r = j * 32 + rsub;
    int ko = (ks ^ (r & 7)) << 3;
    int slot = slot0 + r;
    int s2 = slot < send ? slot : slot0;
    srcA[j] = act + (size_t)s2 * ID + ko;
    srcB[j] = dbase + (size_t)(n0 + r) * ID + ko;
  }
  int dstl = tid << 4;

  int wm = wid >> 1, wn = wid & 1;
  int r16 = lane & 15, kg = lane >> 4;
  int offA[4], offB[4];
  #pragma unroll
  for (int m = 0; m < 4; ++m) {
    int r = wm * 64 + m * 16 + r16;
    offA[m] = r * 128 + ((kg ^ (r & 7)) << 4);
  }
  #pragma unroll
  for (int n = 0; n < 4; ++n) {
    int r = wn * 64 + n * 16 + r16;
    offB[n] = 16384 + r * 128 + ((kg ^ (r & 7)) << 4);
  }

  f32x4 acc[4][4];
  #pragma unroll
  for (int m = 0; m < 4; ++m)
    #pragma unroll
    for (int n = 0; n < 4; ++n) acc[m][n] = (f32x4){0,0,0,0};

  for (int t = 0; t < ID / 64; ++t) {
    barx();
    int ko = t * 64;
    #pragma unroll
    for (int j = 0; j < 4; ++j) gl16(srcA[j] + ko, smem + j * 4096 + dstl);
    #pragma unroll
    for (int j = 0; j < 4; ++j) gl16(srcB[j] + ko, smem + 16384 + j * 4096 + dstl);
    asm volatile("s_waitcnt vmcnt(0)" ::: "memory");
    barx();
    #pragma unroll
    for (int kk = 0; kk < 2; ++kk) {
      bf16x8 fa[4], fb[4];
      #pragma unroll
      for (int m = 0; m < 4; ++m) fa[m] = *(const bf16x8*)(smem + (offA[m] ^ (kk << 6)));
      #pragma unroll
      for (int n = 0; n < 4; ++n) fb[n] = *(const bf16x8*)(smem + (offB[n] ^ (kk << 6)));
      #pragma unroll
      for (int m = 0; m < 4; ++m)
        #pragma unroll
        for (int n = 0; n < 4; ++n)
          acc[m][n] = MFMA16(fa[m], fb[n], acc[m][n], 0, 0, 0);
    }
  }

  // ---- epilogue: scatter rows to out[perm[slot]] ----
  #pragma unroll
  for (int m = 0; m < 4; ++m) {
    int lr = (wm << 6) + (m << 4) + (kg << 2);
    int pr4[4];
    #pragma unroll
    for (int r = 0; r < 4; ++r) {
      int slot = slot0 + lr + r;
      pr4[r] = slot < send ? perm[slot] : -1;
    }
    #pragma unroll
    for (int n = 0; n < 4; ++n) {
      int col = n0 + (wn << 6) + (n << 4) + r16;
      #pragma unroll
      for (int r = 0; r < 4; ++r) {
        if (pr4[r] >= 0) out[(size_t)pr4[r] * HD + col] = acc[m][n][r];
      }
    }
  }
}

extern "C" void kernel_launch(void* const* d_in, const int* in_sizes, int n_in,
                              void* d_out, int out_size, void* d_ws, size_t ws_size,
                              hipStream_t stream) {
  const float* hs = (const float*)d_in[0];
  const float* gw = (const float*)d_in[1];
  const float* uw = (const float*)d_in[2];
  const float* dw = (const float*)d_in[3];
  const int* ids = (const int*)d_in[4];
  float* out = (float*)d_out;

  char* w = (char*)d_ws;
  size_t o = 0;
  int* meta = (int*)(w + o); o += 64;
  int* perm = (int*)(w + o); o += (size_t)TOK * 4;
  o = (o + 255) & ~(size_t)255;
  unsigned short* hid = (unsigned short*)(w + o); o += (size_t)TOK * HD * 2;
  unsigned short* gT  = (unsigned short*)(w + o); o += (size_t)NE * ID * HD * 2;
  unsigned short* uT  = (unsigned short*)(w + o); o += (size_t)NE * ID * HD * 2;
  unsigned short* dT  = (unsigned short*)(w + o); o += (size_t)NE * ID * HD * 2;
  unsigned short* actb = (unsigned short*)(w + o); o += (size_t)TOK * ID * 2;
  // requires ws_size >= ~268.6 MB

  hipLaunchKernelGGL(k_route0, dim3(1), dim3(256), 0, stream, ids, meta);
  hipLaunchKernelGGL(k_route1, dim3(TOK / 256), dim3(256), 0, stream, ids, meta, perm);
  hipLaunchKernelGGL(k_conv, dim3(2048), dim3(256), 0, stream, hs, hid, TOK * HD / 8);
  hipLaunchKernelGGL(k_tr12, dim3(1024, 12), dim3(256), 0, stream, gw, uw, dw, gT, uT, dT);
  hipLaunchKernelGGL(k_gemm1, dim3(MAXMT * 32), dim3(256), 0, stream,
                     hid, gT, uT, meta, perm, actb);
  hipLaunchKernelGGL(k_gemm2, dim3(MAXMT * 8), dim3(256), 0, stream,
                     actb, dT, meta, perm, out);
}